// Round 23
// baseline (55.213 us; speedup 1.0000x reference)
//
#include <hip/hip_runtime.h>
#include <hip/hip_fp16.h>
#include <math.h>

#define NN 4096
// (1/64) * log2(e)  -- folds 1/sqrt(N) and exp->exp2 conversion
#define SCL 0.022542110013890054f
#define LOG2E 1.4426950408889634f

typedef __attribute__((ext_vector_type(8))) _Float16 f16x8;
typedef __attribute__((ext_vector_type(2))) _Float16 f16x2;
typedef __attribute__((ext_vector_type(4))) float f32x4;
typedef __attribute__((ext_vector_type(4))) short s16x4;

__device__ __forceinline__ float exp2_fast(float x) {
  float r; asm("v_exp_f32 %0, %1" : "=v"(r) : "v"(x)); return r;
}
__device__ __forceinline__ unsigned short h16(float x) {
  _Float16 h = (_Float16)x; return *(unsigned short*)&h;
}

// ---------------------------------------------------------------------------
// Kernel 1: Wh = h@W -> fragment-major WhTf (f16); Ei1/Ei2 = dup-half2
// (2^w1s, 2^0.2w1s); Ej1/Ej2 paired-half2. 8 rows/block, grid 2048.
// (adj is consumed directly by k_gat now -- no bits pass.)
// ---------------------------------------------------------------------------
__global__ __launch_bounds__(256)
void k_prep(const float* __restrict__ h, const float* __restrict__ W,
            const float* __restrict__ a, unsigned short* __restrict__ WhTf,
            unsigned* __restrict__ Ei1, unsigned* __restrict__ Ei2,
            unsigned* __restrict__ Ej1, unsigned* __restrict__ Ej2) {
  __shared__ float sW[4096];
  __shared__ unsigned short T[64][8];
  const int t = threadIdx.x;
  const int bi = blockIdx.x;
#pragma unroll
  for (int i = 0; i < 16; ++i) sW[i * 256 + t] = W[i * 256 + t];
  __syncthreads();
  const int wv = t >> 6, lane = t & 63;
  const float a1 = a[lane], a2 = a[64 + lane];
  const int row0 = bi * 8;
  const int q0 = row0 + wv * 2;                  // this wave's even row
  float w1v[2], w2v[2];
  for (int r = 0; r < 2; ++r) {
    const int row = q0 + r;
    const float* hr = h + (size_t)row * 64;
    float acc = 0.f;
#pragma unroll
    for (int k = 0; k < 64; ++k) acc = fmaf(hr[k], sW[k * 64 + lane], acc);
    T[lane][wv * 2 + r] = h16(acc);
    float r1 = acc * a1, r2 = acc * a2;
#pragma unroll
    for (int sft = 32; sft; sft >>= 1) { r1 += __shfl_xor(r1, sft); r2 += __shfl_xor(r2, sft); }
    w1v[r] = r1 * SCL; w2v[r] = r2 * SCL;
  }
  if (lane == 0) {
#pragma unroll
    for (int r = 0; r < 2; ++r) {
      unsigned u1 = h16(exp2_fast(w1v[r]));
      unsigned u2 = h16(exp2_fast(0.2f * w1v[r]));
      Ei1[q0 + r] = u1 | (u1 << 16);
      Ei2[q0 + r] = u2 | (u2 << 16);
    }
    Ej1[q0 >> 1] = (unsigned)h16(exp2_fast(w2v[0])) |
                   ((unsigned)h16(exp2_fast(w2v[1])) << 16);
    Ej2[q0 >> 1] = (unsigned)h16(exp2_fast(0.2f * w2v[0])) |
                   ((unsigned)h16(exp2_fast(0.2f * w2v[1])) << 16);
  }
  __syncthreads();
  // fragment-major store (validated layout, f16 values): (b, ft, g, lane, e)
  // holds Wh[n = g*32 + rg*8 + e][f = ft*16 + jp],  lane = rg*16 + jp.
  const int f = t >> 2, jp4 = t & 3;
  const int b = row0 >> 12, n0 = row0 & 4095;
  const int g32 = n0 >> 5, rgq = (n0 >> 3) & 3;
  unsigned v = *(unsigned*)&T[f][jp4 * 2];
  unsigned short* dst = WhTf +
      ((((size_t)(b * 4 + (f >> 4)) << 7) + g32) << 9) +
      ((rgq * 16 + (f & 15)) << 3) + jp4 * 2;
  *(unsigned*)dst = v;
}

// ---------------------------------------------------------------------------
// Kernel 2: masked-softmax attention partials via f16 MFMA.
// r23: block = (chunk c, 64 i-rows, ALL 4 batches) -> adj read EXACTLY ONCE
// device-wide as a one-time block-cooperative byte-mask stage (fixes r18's
// two failure modes: per-lane gathers and 4x b-redundant adj reads).
// Grid 512 = 8 chunks x 64 i-blocks. Block 512 thr = 8 waves (b = w>>1,
// ih = w&1); wave owns 32 rows x 16 windows (identical per-wave work to r21).
// Stage: 16 coalesced 2KB-per-row int4 passes (8-deep MLP) -> m8[64][520]
// packed bytes (dword writes, conflict-free). Main loop: NO barriers,
// unroll 4; mask via aligned u64 byte-reads. P pair = pk_max(pk_mul(Ei1,Ej1),
// pk_mul(Ei2,Ej2)) masked (exact rank-1 max factorization).
// ---------------------------------------------------------------------------
__global__ __launch_bounds__(512, 2)
void k_gat(const int* __restrict__ adj,
           const unsigned short* __restrict__ WhTf,
           const unsigned* __restrict__ Ei1, const unsigned* __restrict__ Ei2,
           const unsigned* __restrict__ Ej1, const unsigned* __restrict__ Ej2,
           unsigned short* __restrict__ Pp, float* __restrict__ lsp) {
  __shared__ unsigned char m8[64][520];   // byte mask [row][j_local], 33.3 KB

  const int t = threadIdx.x;
  const int w = t >> 6, lane = t & 63;
  const int jp = lane & 15, rg = lane >> 4;
  const int bid = blockIdx.x;
  const int c = bid >> 6;              // 0..7 chunk
  const int i0b = (bid & 63) * 64;     // block row base (64 rows)
  const int b = w >> 1, ih = w & 1;
  const int i0 = i0b + ih * 32;        // wave row base (32 rows)
  const int g0 = c * 16;

  // ---- one-time: adj tile (64 rows x 512 j) -> byte-mask LDS ----
  {
    const int rl = t >> 7;             // 0..3 (row within 4-row stripe)
    const int cb = (t & 127) * 4;      // j_local base (int4)
    const int* __restrict__ src =
        adj + (((size_t)(i0b + rl)) << 12) + c * 512 + cb;
#pragma unroll
    for (int half = 0; half < 2; ++half) {
      int4 va[8];
#pragma unroll
      for (int p = 0; p < 8; ++p)
        va[p] = *(const int4*)(src + (((size_t)(half * 32 + p * 4)) << 12));
#pragma unroll
      for (int p = 0; p < 8; ++p) {
        const int row = half * 32 + p * 4 + rl;
        unsigned pk = (unsigned)(va[p].x != 0) |
                      ((unsigned)(va[p].y != 0) << 8) |
                      ((unsigned)(va[p].z != 0) << 16) |
                      ((unsigned)(va[p].w != 0) << 24);
        *(unsigned*)&m8[row][cb] = pk;   // dword write, conflict-free
      }
    }
  }

  unsigned ei1u[2], ei2u[2];
#pragma unroll
  for (int il = 0; il < 2; ++il) {
    ei1u[il] = Ei1[b * NN + i0 + il * 16 + jp];
    ei2u[il] = Ei2[b * NN + i0 + il * 16 + jp];
  }
  const unsigned short* __restrict__ abase =
      WhTf + (((size_t)(b * 4) << 7) + g0) * 512 + lane * 8;
  const unsigned* __restrict__ ej1b = Ej1 + (b << 11) + (g0 << 4) + (rg << 2);
  const unsigned* __restrict__ ej2b = Ej2 + (b << 11) + (g0 << 4) + (rg << 2);

  f32x4 acc[2][4];                     // [islice][ft]
  f32x4 accd[2];
#pragma unroll
  for (int il = 0; il < 2; ++il) {
    accd[il] = (f32x4){0.f, 0.f, 0.f, 0.f};
#pragma unroll
    for (int ft = 0; ft < 4; ++ft) acc[il][ft] = (f32x4){0.f, 0.f, 0.f, 0.f};
  }
  f16x8 ones;
#pragma unroll
  for (int e = 0; e < 8; ++e) ones[e] = (_Float16)1.0f;

  __syncthreads();   // mask tile ready; no barriers below

#pragma unroll 4
  for (int jt = 0; jt < 16; ++jt) {
    const f16x8 af0 = *(const f16x8*)(abase + (0 * 128 + jt) * 512);
    const f16x8 af1 = *(const f16x8*)(abase + (1 * 128 + jt) * 512);
    const f16x8 af2 = *(const f16x8*)(abase + (2 * 128 + jt) * 512);
    const f16x8 af3 = *(const f16x8*)(abase + (3 * 128 + jt) * 512);
    const uint4 e1p = *(const uint4*)(ej1b + jt * 16);
    const uint4 e2p = *(const uint4*)(ej2b + jt * 16);
    const unsigned e1a[4] = {e1p.x, e1p.y, e1p.z, e1p.w};
    const unsigned e2a[4] = {e2p.x, e2p.y, e2p.z, e2p.w};

    f16x8 pf[2];
#pragma unroll
    for (int il = 0; il < 2; ++il) {
      const unsigned long long mv = *(const unsigned long long*)
          &m8[ih * 32 + il * 16 + jp][jt * 32 + rg * 8];
      const f16x2 x1 = *(const f16x2*)&ei1u[il];
      const f16x2 x2 = *(const f16x2*)&ei2u[il];
      unsigned pw[4];
#pragma unroll
      for (int p4 = 0; p4 < 4; ++p4) {
        f16x2 c1 = x1 * (*(const f16x2*)&e1a[p4]);
        f16x2 c2 = x2 * (*(const f16x2*)&e2a[p4]);
        f16x2 mx = __builtin_elementwise_max(c1, c2);  // exp2(leaky(s)) pair
        unsigned mexp = (((mv >> (16 * p4)) & 0xFFull) ? 0xFFFFu : 0u) |
                        (((mv >> (16 * p4 + 8)) & 0xFFull) ? 0xFFFF0000u : 0u);
        pw[p4] = (*(unsigned*)&mx) & mexp;     // adjacency mask -> +0.0
      }
      pf[il] = *(f16x8*)pw;
    }
#pragma unroll
    for (int il = 0; il < 2; ++il) {
      accd[il] = __builtin_amdgcn_mfma_f32_16x16x32_f16(ones, pf[il], accd[il], 0, 0, 0);
      acc[il][0] = __builtin_amdgcn_mfma_f32_16x16x32_f16(af0, pf[il], acc[il][0], 0, 0, 0);
      acc[il][1] = __builtin_amdgcn_mfma_f32_16x16x32_f16(af1, pf[il], acc[il][1], 0, 0, 0);
      acc[il][2] = __builtin_amdgcn_mfma_f32_16x16x32_f16(af2, pf[il], acc[il][2], 0, 0, 0);
      acc[il][3] = __builtin_amdgcn_mfma_f32_16x16x32_f16(af3, pf[il], acc[il][3], 0, 0, 0);
    }
  }

  // denominator partials (all D rows identical; take reg 0 at rg==0)
  if (rg == 0) {
#pragma unroll
    for (int il = 0; il < 2; ++il)
      lsp[(size_t)(c * 4 + b) * NN + i0 + il * 16 + jp] = accd[il][0];
  }
  // unnormalized f16 partials: acc[il][ft][r] = D[f=ft*16+rg*4+r][i=i0+il*16+jp]
  const size_t pbase = (((size_t)(c * 4 + b)) * NN + i0) * 64;
#pragma unroll
  for (int il = 0; il < 2; ++il)
#pragma unroll
    for (int ft = 0; ft < 4; ++ft) {
      s16x4 pk;
#pragma unroll
      for (int r = 0; r < 4; ++r) pk[r] = (short)h16(acc[il][ft][r]);
      *(s16x4*)(Pp + pbase + (size_t)(il * 16 + jp) * 64 + ft * 16 + rg * 4) = pk;
    }
}

// ---------------------------------------------------------------------------
// Kernel 3: combine 8 chunk partials, normalize, BN + ELU (r21-validated).
// Block 256 = 4 waves (wave = batch); 8 nodes/block, grid 512.
// Lane -> (node_local = lane>>3, f-slice = lane&7): f16x8 chunk loads.
// ---------------------------------------------------------------------------
__global__ __launch_bounds__(256)
void k_bn(const float* __restrict__ h, const unsigned short* __restrict__ Pp,
          const float* __restrict__ lsp, const float* __restrict__ gamma,
          const float* __restrict__ beta, float* __restrict__ out) {
  __shared__ float bnp[8][4][2];
  const int t = threadIdx.x;
  const int w = t >> 6, lane = t & 63;   // w = batch
  const int nl = lane >> 3, fs = lane & 7;
  const int i = blockIdx.x * 8 + nl;

  float xa[8] = {0.f, 0.f, 0.f, 0.f, 0.f, 0.f, 0.f, 0.f};
  float lt = 0.f;
#pragma unroll
  for (int cc = 0; cc < 8; ++cc) {
    const size_t base = ((size_t)(cc * 4 + w) * NN + i);
    f16x8 v = *(const f16x8*)(Pp + base * 64 + fs * 8);
#pragma unroll
    for (int k = 0; k < 8; ++k) xa[k] += (float)v[k];
    lt += lsp[base];
  }
  const float invl = 1.f / lt;
  float s1 = 0.f, s2 = 0.f;
#pragma unroll
  for (int k = 0; k < 8; ++k) {
    xa[k] *= invl;
    s1 += xa[k]; s2 += xa[k] * xa[k];
  }
  s1 += __shfl_xor(s1, 1); s2 += __shfl_xor(s2, 1);
  s1 += __shfl_xor(s1, 2); s2 += __shfl_xor(s2, 2);
  s1 += __shfl_xor(s1, 4); s2 += __shfl_xor(s2, 4);
  if (fs == 0) { bnp[nl][w][0] = s1; bnp[nl][w][1] = s2; }
  __syncthreads();
  const float t1 = bnp[nl][0][0] + bnp[nl][1][0] + bnp[nl][2][0] + bnp[nl][3][0];
  const float t2 = bnp[nl][0][1] + bnp[nl][1][1] + bnp[nl][2][1] + bnp[nl][3][1];
  const float mean = t1 * (1.f / 256.f);
  const float var  = t2 * (1.f / 256.f) - mean * mean;
  const float sc = gamma[i] * rsqrtf(var + 1e-5f);
  const float bt = beta[i];
  const size_t off = (((size_t)(w * NN + i)) << 6) + fs * 8;
  const float4 hv0 = *(const float4*)(h + off);
  const float4 hv1 = *(const float4*)(h + off + 4);
  const float hvv[8] = {hv0.x, hv0.y, hv0.z, hv0.w, hv1.x, hv1.y, hv1.z, hv1.w};
  float o[8];
#pragma unroll
  for (int k = 0; k < 8; ++k) {
    float v = sc * (xa[k] - mean) + bt + hvv[k];
    o[k] = v > 0.f ? v : exp2_fast(v * LOG2E) - 1.f;
  }
  *(float4*)(out + off)     = make_float4(o[0], o[1], o[2], o[3]);
  *(float4*)(out + off + 4) = make_float4(o[4], o[5], o[6], o[7]);
}

// ---------------------------------------------------------------------------
extern "C" void kernel_launch(void* const* d_in, const int* in_sizes, int n_in,
                              void* d_out, int out_size, void* d_ws, size_t ws_size,
                              hipStream_t stream) {
  (void)in_sizes; (void)n_in; (void)out_size; (void)ws_size;
  const float* h     = (const float*)d_in[0];
  const int*   adj   = (const int*)d_in[1];
  const float* W     = (const float*)d_in[2];
  const float* a     = (const float*)d_in[3];
  const float* gamma = (const float*)d_in[4];
  const float* beta  = (const float*)d_in[5];
  float* out = (float*)d_out;

  char* ws = (char*)d_ws;
  unsigned short* WhTf = (unsigned short*)ws;                 // 2 MB @ 0
  unsigned* Ei1 = (unsigned*)(ws + (4u << 20));               // 64 KB
  unsigned* Ei2 = (unsigned*)(ws + (4u << 20) + (64u << 10)); // 64 KB
  unsigned* Ej1 = (unsigned*)(ws + (4u << 20) + (128u << 10)); // 32 KB
  unsigned* Ej2 = (unsigned*)(ws + (4u << 20) + (160u << 10)); // 32 KB
  float* lsp = (float*)(ws + (4u << 20) + (192u << 10));      // 512 KB
  unsigned short* Pp = (unsigned short*)(ws + (5u << 20));    // 16.8 MB

  k_prep<<<2048, 256, 0, stream>>>(h, W, a, WhTf, Ei1, Ei2, Ej1, Ej2);
  k_gat<<<512, 512, 0, stream>>>(adj, WhTf, Ei1, Ei2, Ej1, Ej2, Pp, lsp);
  k_bn<<<512, 256, 0, stream>>>(h, Pp, lsp, gamma, beta, out);
}

// Round 24
// 45.711 us; speedup vs baseline: 1.2079x; 1.2079x over previous
//
#include <hip/hip_runtime.h>
#include <hip/hip_fp16.h>
#include <math.h>

#define NN 4096
// (1/64) * log2(e)  -- folds 1/sqrt(N) and exp->exp2 conversion
#define SCL 0.022542110013890054f
#define LOG2E 1.4426950408889634f

typedef __attribute__((ext_vector_type(8))) _Float16 f16x8;
typedef __attribute__((ext_vector_type(2))) _Float16 f16x2;
typedef __attribute__((ext_vector_type(4))) float f32x4;
typedef __attribute__((ext_vector_type(4))) short s16x4;

__device__ __forceinline__ float exp2_fast(float x) {
  float r; asm("v_exp_f32 %0, %1" : "=v"(r) : "v"(x)); return r;
}
__device__ __forceinline__ unsigned short h16(float x) {
  _Float16 h = (_Float16)x; return *(unsigned short*)&h;
}

// ---------------------------------------------------------------------------
// Kernel 1 (interleaved block roles -- adj BW work overlaps Wh compute):
//   bid % 3 == 0 (1024 blocks): adj -> bits[i][g] via coalesced dword-ballot,
//     1 row/wave, all 32 loads issued first (MLP), lane l latches word l.
//   else (2048 blocks):          Wh = h@W -> fragment-major WhTf (f16);
//     Ei1/Ei2 = dup-half2(2^w1s, 2^0.2w1s); Ej1/Ej2 paired-half2.
// (r21-validated configuration; r22/r23 adj variants both regressed.)
// ---------------------------------------------------------------------------
__global__ __launch_bounds__(256)
void k_prep(const float* __restrict__ h, const float* __restrict__ W,
            const float* __restrict__ a, const int* __restrict__ adj,
            unsigned short* __restrict__ WhTf, unsigned* __restrict__ Ei1,
            unsigned* __restrict__ Ei2, unsigned* __restrict__ Ej1,
            unsigned* __restrict__ Ej2, unsigned* __restrict__ bits) {
  __shared__ float sW[4096];
  __shared__ unsigned short T[64][8];
  const int t = threadIdx.x;
  const int bi = blockIdx.x;
  const int r3 = bi % 3, q3 = bi / 3;
  if (r3 == 0) {
    const int w = t >> 6, lane = t & 63;
    const int r = q3 * 4 + w;                    // one row per wave
    const int kq = lane >> 1, hi = lane & 1;
#pragma unroll
    for (int half = 0; half < 2; ++half) {
      const int* __restrict__ src = adj + ((size_t)r << 12) + half * 2048;
      int v[32];
#pragma unroll
      for (int k = 0; k < 32; ++k) v[k] = src[k * 64 + lane];   // all in flight
      unsigned myw = 0;
#pragma unroll
      for (int k = 0; k < 32; ++k) {
        unsigned long long m = __ballot(v[k] != 0);
        unsigned lohi = hi ? (unsigned)(m >> 32) : (unsigned)m;
        myw = (kq == k) ? lohi : myw;
      }
      bits[((size_t)r << 7) + half * 64 + lane] = myw;
    }
    return;
  }
  // ---- Wh path: 8 rows (same batch) per block ----
#pragma unroll
  for (int i = 0; i < 16; ++i) sW[i * 256 + t] = W[i * 256 + t];
  __syncthreads();
  const int wv = t >> 6, lane = t & 63;
  const float a1 = a[lane], a2 = a[64 + lane];
  const int row0 = (q3 * 2 + (r3 - 1)) * 8;
  const int q0 = row0 + wv * 2;                  // this wave's even row
  float w1v[2], w2v[2];
  for (int r = 0; r < 2; ++r) {
    const int row = q0 + r;
    const float* hr = h + (size_t)row * 64;
    float acc = 0.f;
#pragma unroll
    for (int k = 0; k < 64; ++k) acc = fmaf(hr[k], sW[k * 64 + lane], acc);
    T[lane][wv * 2 + r] = h16(acc);
    float r1 = acc * a1, r2 = acc * a2;
#pragma unroll
    for (int sft = 32; sft; sft >>= 1) { r1 += __shfl_xor(r1, sft); r2 += __shfl_xor(r2, sft); }
    w1v[r] = r1 * SCL; w2v[r] = r2 * SCL;
  }
  if (lane == 0) {
#pragma unroll
    for (int r = 0; r < 2; ++r) {
      unsigned u1 = h16(exp2_fast(w1v[r]));
      unsigned u2 = h16(exp2_fast(0.2f * w1v[r]));
      Ei1[q0 + r] = u1 | (u1 << 16);
      Ei2[q0 + r] = u2 | (u2 << 16);
    }
    Ej1[q0 >> 1] = (unsigned)h16(exp2_fast(w2v[0])) |
                   ((unsigned)h16(exp2_fast(w2v[1])) << 16);
    Ej2[q0 >> 1] = (unsigned)h16(exp2_fast(0.2f * w2v[0])) |
                   ((unsigned)h16(exp2_fast(0.2f * w2v[1])) << 16);
  }
  __syncthreads();
  // fragment-major store (validated layout, f16 values): (b, ft, g, lane, e)
  // holds Wh[n = g*32 + rg*8 + e][f = ft*16 + jp],  lane = rg*16 + jp.
  const int f = t >> 2, jp4 = t & 3;
  const int b = row0 >> 12, n0 = row0 & 4095;
  const int g32 = n0 >> 5, rgq = (n0 >> 3) & 3;
  unsigned v = *(unsigned*)&T[f][jp4 * 2];
  unsigned short* dst = WhTf +
      ((((size_t)(b * 4 + (f >> 4)) << 7) + g32) << 9) +
      ((rgq * 16 + (f & 15)) << 3) + jp4 * 2;
  *(unsigned*)dst = v;
}

// ---------------------------------------------------------------------------
// Kernel 2: masked-softmax attention partials via f16 MFMA, big-tile blocks.
// Grid 512 = 8 chunks x 4 b x 16 i-blocks (256 i). Block 512 thr = 8 waves;
// wave w owns i-rows [i0b+32w, +32) (2 islices), sweeps the chunk's 16
// windows. NO staging, NO barriers in main loop. r24: unroll 8 (r21's
// unroll 2->4 bought 4 us; VGPR headroom allows 8 windows of loads in
// flight). P pair = pk_max(pk_mul(Ei1,Ej1), pk_mul(Ei2,Ej2)) & bitmask.
// ---------------------------------------------------------------------------
__global__ __launch_bounds__(512, 2)
void k_gat(const unsigned* __restrict__ bits,
           const unsigned short* __restrict__ WhTf,
           const unsigned* __restrict__ Ei1, const unsigned* __restrict__ Ei2,
           const unsigned* __restrict__ Ej1, const unsigned* __restrict__ Ej2,
           unsigned short* __restrict__ Pp, float* __restrict__ lsp) {
  __shared__ unsigned mlds[256][17];   // [row][window] mask words, 17.4 KB

  const int t = threadIdx.x;
  const int w = t >> 6, lane = t & 63;
  const int jp = lane & 15, rg = lane >> 4;
  const int bid = blockIdx.x;
  const int c = bid >> 6;              // 0..7 chunk
  const int b = (bid >> 4) & 3;
  const int i0b = (bid & 15) * 256;    // block row base
  const int i0 = i0b + w * 32;         // wave row base (32 rows/wave)
  const int g0 = c * 16;

  // one-time: mask tile (coalesced; 32 rows x 16 words per pass, 8 passes)
#pragma unroll
  for (int pass = 0; pass < 8; ++pass) {
    const int row = pass * 32 + (t >> 4);
    mlds[row][t & 15] = bits[((size_t)(i0b + row) << 7) + g0 + (t & 15)];
  }

  unsigned ei1u[2], ei2u[2];
#pragma unroll
  for (int il = 0; il < 2; ++il) {
    ei1u[il] = Ei1[b * NN + i0 + il * 16 + jp];
    ei2u[il] = Ei2[b * NN + i0 + il * 16 + jp];
  }
  const unsigned short* __restrict__ abase =
      WhTf + (((size_t)(b * 4) << 7) + g0) * 512 + lane * 8;
  const unsigned* __restrict__ ej1b = Ej1 + (b << 11) + (g0 << 4) + (rg << 2);
  const unsigned* __restrict__ ej2b = Ej2 + (b << 11) + (g0 << 4) + (rg << 2);

  f32x4 acc[2][4];                     // [islice][ft]
  f32x4 accd[2];
#pragma unroll
  for (int il = 0; il < 2; ++il) {
    accd[il] = (f32x4){0.f, 0.f, 0.f, 0.f};
#pragma unroll
    for (int ft = 0; ft < 4; ++ft) acc[il][ft] = (f32x4){0.f, 0.f, 0.f, 0.f};
  }
  f16x8 ones;
#pragma unroll
  for (int e = 0; e < 8; ++e) ones[e] = (_Float16)1.0f;

  __syncthreads();   // mask tile ready; no barriers below

#pragma unroll 8
  for (int jt = 0; jt < 16; ++jt) {
    const f16x8 af0 = *(const f16x8*)(abase + (0 * 128 + jt) * 512);
    const f16x8 af1 = *(const f16x8*)(abase + (1 * 128 + jt) * 512);
    const f16x8 af2 = *(const f16x8*)(abase + (2 * 128 + jt) * 512);
    const f16x8 af3 = *(const f16x8*)(abase + (3 * 128 + jt) * 512);
    const uint4 e1p = *(const uint4*)(ej1b + jt * 16);
    const uint4 e2p = *(const uint4*)(ej2b + jt * 16);
    const unsigned e1a[4] = {e1p.x, e1p.y, e1p.z, e1p.w};
    const unsigned e2a[4] = {e2p.x, e2p.y, e2p.z, e2p.w};

    f16x8 pf[2];
#pragma unroll
    for (int il = 0; il < 2; ++il) {
      const unsigned mb = mlds[w * 32 + il * 16 + jp][jt] >> (rg * 8);
      const f16x2 x1 = *(const f16x2*)&ei1u[il];
      const f16x2 x2 = *(const f16x2*)&ei2u[il];
      unsigned pw[4];
#pragma unroll
      for (int p4 = 0; p4 < 4; ++p4) {
        f16x2 c1 = x1 * (*(const f16x2*)&e1a[p4]);
        f16x2 c2 = x2 * (*(const f16x2*)&e2a[p4]);
        f16x2 mx = __builtin_elementwise_max(c1, c2);  // exp2(leaky(s)) pair
        unsigned mexp = (((mb >> (2 * p4)) & 1u) ? 0xFFFFu : 0u) |
                        (((mb >> (2 * p4 + 1)) & 1u) ? 0xFFFF0000u : 0u);
        pw[p4] = (*(unsigned*)&mx) & mexp;     // adjacency mask -> +0.0
      }
      pf[il] = *(f16x8*)pw;
    }
#pragma unroll
    for (int il = 0; il < 2; ++il) {
      accd[il] = __builtin_amdgcn_mfma_f32_16x16x32_f16(ones, pf[il], accd[il], 0, 0, 0);
      acc[il][0] = __builtin_amdgcn_mfma_f32_16x16x32_f16(af0, pf[il], acc[il][0], 0, 0, 0);
      acc[il][1] = __builtin_amdgcn_mfma_f32_16x16x32_f16(af1, pf[il], acc[il][1], 0, 0, 0);
      acc[il][2] = __builtin_amdgcn_mfma_f32_16x16x32_f16(af2, pf[il], acc[il][2], 0, 0, 0);
      acc[il][3] = __builtin_amdgcn_mfma_f32_16x16x32_f16(af3, pf[il], acc[il][3], 0, 0, 0);
    }
  }

  // denominator partials (all D rows identical; take reg 0 at rg==0)
  if (rg == 0) {
#pragma unroll
    for (int il = 0; il < 2; ++il)
      lsp[(size_t)(c * 4 + b) * NN + i0 + il * 16 + jp] = accd[il][0];
  }
  // unnormalized f16 partials: acc[il][ft][r] = D[f=ft*16+rg*4+r][i=i0+il*16+jp]
  const size_t pbase = (((size_t)(c * 4 + b)) * NN + i0) * 64;
#pragma unroll
  for (int il = 0; il < 2; ++il)
#pragma unroll
    for (int ft = 0; ft < 4; ++ft) {
      s16x4 pk;
#pragma unroll
      for (int r = 0; r < 4; ++r) pk[r] = (short)h16(acc[il][ft][r]);
      *(s16x4*)(Pp + pbase + (size_t)(il * 16 + jp) * 64 + ft * 16 + rg * 4) = pk;
    }
}

// ---------------------------------------------------------------------------
// Kernel 3: combine 8 chunk partials, normalize, BN + ELU (r21-validated).
// Block 256 = 4 waves (wave = batch); 8 nodes/block, grid 512.
// Lane -> (node_local = lane>>3, f-slice = lane&7): f16x8 chunk loads.
// ---------------------------------------------------------------------------
__global__ __launch_bounds__(256)
void k_bn(const float* __restrict__ h, const unsigned short* __restrict__ Pp,
          const float* __restrict__ lsp, const float* __restrict__ gamma,
          const float* __restrict__ beta, float* __restrict__ out) {
  __shared__ float bnp[8][4][2];
  const int t = threadIdx.x;
  const int w = t >> 6, lane = t & 63;   // w = batch
  const int nl = lane >> 3, fs = lane & 7;
  const int i = blockIdx.x * 8 + nl;

  float xa[8] = {0.f, 0.f, 0.f, 0.f, 0.f, 0.f, 0.f, 0.f};
  float lt = 0.f;
#pragma unroll
  for (int cc = 0; cc < 8; ++cc) {
    const size_t base = ((size_t)(cc * 4 + w) * NN + i);
    f16x8 v = *(const f16x8*)(Pp + base * 64 + fs * 8);
#pragma unroll
    for (int k = 0; k < 8; ++k) xa[k] += (float)v[k];
    lt += lsp[base];
  }
  const float invl = 1.f / lt;
  float s1 = 0.f, s2 = 0.f;
#pragma unroll
  for (int k = 0; k < 8; ++k) {
    xa[k] *= invl;
    s1 += xa[k]; s2 += xa[k] * xa[k];
  }
  s1 += __shfl_xor(s1, 1); s2 += __shfl_xor(s2, 1);
  s1 += __shfl_xor(s1, 2); s2 += __shfl_xor(s2, 2);
  s1 += __shfl_xor(s1, 4); s2 += __shfl_xor(s2, 4);
  if (fs == 0) { bnp[nl][w][0] = s1; bnp[nl][w][1] = s2; }
  __syncthreads();
  const float t1 = bnp[nl][0][0] + bnp[nl][1][0] + bnp[nl][2][0] + bnp[nl][3][0];
  const float t2 = bnp[nl][0][1] + bnp[nl][1][1] + bnp[nl][2][1] + bnp[nl][3][1];
  const float mean = t1 * (1.f / 256.f);
  const float var  = t2 * (1.f / 256.f) - mean * mean;
  const float sc = gamma[i] * rsqrtf(var + 1e-5f);
  const float bt = beta[i];
  const size_t off = (((size_t)(w * NN + i)) << 6) + fs * 8;
  const float4 hv0 = *(const float4*)(h + off);
  const float4 hv1 = *(const float4*)(h + off + 4);
  const float hvv[8] = {hv0.x, hv0.y, hv0.z, hv0.w, hv1.x, hv1.y, hv1.z, hv1.w};
  float o[8];
#pragma unroll
  for (int k = 0; k < 8; ++k) {
    float v = sc * (xa[k] - mean) + bt + hvv[k];
    o[k] = v > 0.f ? v : exp2_fast(v * LOG2E) - 1.f;
  }
  *(float4*)(out + off)     = make_float4(o[0], o[1], o[2], o[3]);
  *(float4*)(out + off + 4) = make_float4(o[4], o[5], o[6], o[7]);
}

// ---------------------------------------------------------------------------
extern "C" void kernel_launch(void* const* d_in, const int* in_sizes, int n_in,
                              void* d_out, int out_size, void* d_ws, size_t ws_size,
                              hipStream_t stream) {
  (void)in_sizes; (void)n_in; (void)out_size; (void)ws_size;
  const float* h     = (const float*)d_in[0];
  const int*   adj   = (const int*)d_in[1];
  const float* W     = (const float*)d_in[2];
  const float* a     = (const float*)d_in[3];
  const float* gamma = (const float*)d_in[4];
  const float* beta  = (const float*)d_in[5];
  float* out = (float*)d_out;

  char* ws = (char*)d_ws;
  unsigned short* WhTf = (unsigned short*)ws;                 // 2 MB @ 0
  unsigned* bits = (unsigned*)(ws + (2u << 20));              // 2 MB @ 2M
  unsigned* Ei1 = (unsigned*)(ws + (4u << 20));               // 64 KB
  unsigned* Ei2 = (unsigned*)(ws + (4u << 20) + (64u << 10)); // 64 KB
  unsigned* Ej1 = (unsigned*)(ws + (4u << 20) + (128u << 10)); // 32 KB
  unsigned* Ej2 = (unsigned*)(ws + (4u << 20) + (160u << 10)); // 32 KB
  float* lsp = (float*)(ws + (4u << 20) + (192u << 10));      // 512 KB
  unsigned short* Pp = (unsigned short*)(ws + (5u << 20));    // 16.8 MB

  k_prep<<<3072, 256, 0, stream>>>(h, W, a, adj, WhTf, Ei1, Ei2, Ej1, Ej2, bits);
  k_gat<<<512, 512, 0, stream>>>(bits, WhTf, Ei1, Ei2, Ej1, Ej2, Pp, lsp);
  k_bn<<<512, 256, 0, stream>>>(h, Pp, lsp, gamma, beta, out);
}